// Round 17
// baseline (197.595 us; speedup 1.0000x reference)
//
#include <hip/hip_runtime.h>
#include <stdint.h>

typedef __attribute__((ext_vector_type(8))) short bf16x8;
typedef __attribute__((ext_vector_type(4))) float f32x4;
typedef __attribute__((ext_vector_type(16))) float f32x16;
typedef __attribute__((ext_vector_type(4))) unsigned short u16x4;

static constexpr int Bn = 4, Sn = 2048, Dn = 1024, Hn = 16, HD = 64;
static constexpr int Mrows = Bn * Sn;   // 8192
static constexpr int D3 = 3 * Dn;       // 3072

__device__ __forceinline__ unsigned short f2bf(float f) {
  unsigned int u = __float_as_uint(f);
  u += 0x7FFF + ((u >> 16) & 1);
  return (unsigned short)(u >> 16);
}

__device__ __forceinline__ void gload16(const void* gptr, void* lptr) {
  __builtin_amdgcn_global_load_lds(
      (__attribute__((address_space(1))) void*)gptr,
      (__attribute__((address_space(3))) void*)lptr, 16, 0, 0);
}

__device__ __forceinline__ int swz8(int r) { return (r ^ (r >> 3)) & 7; }

__device__ __forceinline__ float vexp2(float x) {
#if __has_builtin(__builtin_amdgcn_exp2f)
  return __builtin_amdgcn_exp2f(x);
#else
  return exp2f(x);
#endif
}

__device__ __forceinline__ unsigned cvtpk(float lo, float hi) {
  unsigned r;
  asm("v_cvt_pk_bf16_f32 %0, %1, %2" : "=v"(r) : "v"(lo), "v"(hi));
  return r;
}

__device__ __forceinline__ float lanepull(float v, int srclane) {
  return __int_as_float(__builtin_amdgcn_ds_bpermute(srclane * 4, __float_as_int(v)));
}

// ---------------- elementwise f32 -> bf16 ----------------
__global__ void cvt_f32_bf16(const float* __restrict__ in,
                             unsigned short* __restrict__ out, int n) {
  int i = (blockIdx.x * blockDim.x + threadIdx.x) * 4;
  if (i < n) {
    const float4 v = *(const float4*)(in + i);
    u16x4 o;
    o.x = f2bf(v.x); o.y = f2bf(v.y); o.z = f2bf(v.z); o.w = f2bf(v.w);
    *(u16x4*)(out + i) = o;
  }
}

// ---------------- W [K][N] f32 -> W^T [N][K] bf16 ----------------
__global__ void transpose_cvt(const float* __restrict__ W,
                              unsigned short* __restrict__ Wt, int K, int N) {
  __shared__ float tile[32][33];
  const int n0 = blockIdx.x * 32, k0 = blockIdx.y * 32;
  const int tx = threadIdx.x, ty = threadIdx.y;   // block (32,8)
  #pragma unroll
  for (int j = 0; j < 4; j++)
    tile[ty + 8 * j][tx] = W[(size_t)(k0 + ty + 8 * j) * N + n0 + tx];
  __syncthreads();
  #pragma unroll
  for (int j = 0; j < 4; j++)
    Wt[(size_t)(n0 + ty + 8 * j) * K + k0 + tx] = f2bf(tile[tx][ty + 8 * j]);
}

// ---------------- 256x256 bf16 GEMM, BK=64 (m201-template geometry) ----------------
// 8 waves 2Mx4N, per-wave 128x64 (acc 8x4 f32x4 = 128 VGPR). 128 KB dbuf LDS,
// 1 blk/CU (launch_bounds(512,1) -> VGPR cap 256). Key lever vs 128-row tiles:
// 64 MFMA per K-tile per wave (2x arithmetic intensity per staged byte).
// Staging: 4 half-tiles (128 rows x 64 bf16) per K-tile, 2 gloads/thread each.
// Per K-tile: issue 3 half-tiles of t+1 -> vmcnt(6) retires ALL of tile t
// (2 loads x 3 half-tiles in flight, template derivation) -> barrier ->
// issue 4th half-tile -> 4 Gray-order compute sub-phases (16 MFMA each,
// interleaved loadA/loadB; compiler emits fine lgkm) -> lgkm(0)+barrier
// (readers retired before buffer overwrite next iter).
template<bool BF16_OUT>
__global__ __launch_bounds__(512, 1)
void gemm_256(const unsigned short* __restrict__ A,
              const unsigned short* __restrict__ Bt,
              const float* __restrict__ bias,
              void* __restrict__ Cout, int Nt, int Kt) {
  __shared__ __align__(128) unsigned char smem[131072];  // 2 x (A 32K + B 32K)
  const int tid = threadIdx.x;
  const int w = tid >> 6, lane = tid & 63;
  const int wm = w >> 2, wn = w & 3;
  const int lrow = lane & 15, lk = lane >> 4;
  const long brow = (long)blockIdx.x * 256;
  const long bcol = (long)blockIdx.y * 256;

  // stage one 128-row half (h) of a [256][Kt] operand into LDS buf (2 gloads)
  auto stage_half = [&](const unsigned short* M, long bof, int h, int k0,
                        unsigned char* buf) {
    #pragma unroll
    for (int i = 0; i < 2; i++) {
      const int r = h * 128 + i * 64 + w * 8 + (lane >> 3);
      gload16(M + (size_t)(bof + r) * Kt + k0 + (((lane & 7) ^ swz8(r)) * 8),
              buf + (size_t)(h * 128 + i * 64 + w * 8) * 128);
    }
  };

  f32x4 acc[8][4] = {};

  // prologue: tile 0 fully staged (8 loads outstanding)
  stage_half(A,  brow, 0, 0, smem);
  stage_half(Bt, bcol, 0, 0, smem + 32768);
  stage_half(A,  brow, 1, 0, smem);
  stage_half(Bt, bcol, 1, 0, smem + 32768);

  const int ntile = Kt >> 6;
  for (int t = 0; t < ntile; t++) {
    const int cur = t & 1;
    unsigned char* Ab = smem + cur * 65536;
    unsigned char* Bb = Ab + 32768;
    unsigned char* An = smem + (cur ^ 1) * 65536;
    unsigned char* Bn = An + 32768;
    const bool pre = (t + 1 < ntile);
    const int kn = (t + 1) << 6;

    if (pre) {                        // 3 half-tiles of t+1 in flight (6 loads)
      stage_half(A,  brow, 0, kn, An);
      stage_half(Bt, bcol, 0, kn, Bn);
      stage_half(A,  brow, 1, kn, An);
      asm volatile("s_waitcnt vmcnt(6)" ::: "memory");  // retires all of tile t
    } else {
      asm volatile("s_waitcnt vmcnt(0)" ::: "memory");
    }
    __builtin_amdgcn_sched_barrier(0);
    __builtin_amdgcn_s_barrier();     // tile t visible block-wide
    __builtin_amdgcn_sched_barrier(0);
    if (pre) stage_half(Bt, bcol, 1, kn, Bn);   // 4th half-tile (2 loads)

    // ---- compute tile t: 4 Gray-order sub-phases, 64 MFMA/wave ----
    bf16x8 af[4][2], bfv[2][2];
    auto loadA = [&](int q) {
      #pragma unroll
      for (int fr = 0; fr < 4; fr++) {
        const int r = wm * 128 + q * 64 + fr * 16 + lrow;
        #pragma unroll
        for (int kk = 0; kk < 2; kk++)
          af[fr][kk] = *(const bf16x8*)(Ab + r * 128 + (((kk * 4 + lk) ^ swz8(r)) * 16));
      }
    };
    auto loadB = [&](int bs) {
      #pragma unroll
      for (int fc = 0; fc < 2; fc++) {
        const int r = wn * 64 + bs * 32 + fc * 16 + lrow;
        #pragma unroll
        for (int kk = 0; kk < 2; kk++)
          bfv[fc][kk] = *(const bf16x8*)(Bb + r * 128 + (((kk * 4 + lk) ^ swz8(r)) * 16));
      }
    };
    auto mma = [&](int q, int bs) {
      __builtin_amdgcn_s_setprio(1);
      #pragma unroll
      for (int fr = 0; fr < 4; fr++)
        #pragma unroll
        for (int fc = 0; fc < 2; fc++) {
          acc[q * 4 + fr][bs * 2 + fc] = __builtin_amdgcn_mfma_f32_16x16x32_bf16(
              af[fr][0], bfv[fc][0], acc[q * 4 + fr][bs * 2 + fc], 0, 0, 0);
          acc[q * 4 + fr][bs * 2 + fc] = __builtin_amdgcn_mfma_f32_16x16x32_bf16(
              af[fr][1], bfv[fc][1], acc[q * 4 + fr][bs * 2 + fc], 0, 0, 0);
        }
      __builtin_amdgcn_s_setprio(0);
    };
    loadA(0); loadB(0); mma(0, 0);
    loadB(1);           mma(0, 1);
    loadA(1);           mma(1, 1);
    loadB(0);           mma(1, 0);

    asm volatile("s_waitcnt lgkmcnt(0)" ::: "memory");  // reads done before overwrite
    __builtin_amdgcn_sched_barrier(0);
    __builtin_amdgcn_s_barrier();
  }

  #pragma unroll
  for (int fc2 = 0; fc2 < 4; fc2++) {
    const long col = bcol + wn * 64 + fc2 * 16 + lrow;
    const float bv = bias[col];
    #pragma unroll
    for (int ar = 0; ar < 8; ar++) {
      #pragma unroll
      for (int rr = 0; rr < 4; rr++) {
        const long row = brow + wm * 128 + ar * 16 + lk * 4 + rr;
        const float v = acc[ar][fc2][rr] + bv;
        if (BF16_OUT)
          ((unsigned short*)Cout)[row * Nt + col] = f2bf(v);
        else
          ((float*)Cout)[row * Nt + col] = v;
      }
    }
  }
}

// ---------------- 128x256 bf16 GEMM (bt2, round-13 proven; used for proj) ----------------
template<bool BF16_OUT>
__global__ __launch_bounds__(512, 1)
void gemm_bt2(const unsigned short* __restrict__ A,
              const unsigned short* __restrict__ Bt,
              const float* __restrict__ bias,
              void* __restrict__ Cout, int Nt, int Kt) {
  __shared__ __align__(128) unsigned char smem[98304];  // 2 x (A 16K + B 32K)
  const int tid = threadIdx.x;
  const int w = tid >> 6, lane = tid & 63;
  const int wm = w >> 2, wn = w & 3;
  const int lrow = lane & 15, lk = lane >> 4;
  const long brow = (long)blockIdx.x * 128;
  const long bcol = (long)blockIdx.y * 256;

  const int srow = tid >> 3;    // 0..63
  const int sslot = tid & 7;

  auto stage = [&](int k0, unsigned char* buf) {   // 6 gloads: 2 A + 4 B
    unsigned char* Ab = buf;
    unsigned char* Bb = buf + 16384;
    #pragma unroll
    for (int i = 0; i < 2; i++) {
      const int r = srow + 64 * i;
      gload16(A + (size_t)(brow + r) * Kt + k0 + ((sslot ^ swz8(r)) * 8),
              Ab + w * 1024 + i * 8192);
    }
    #pragma unroll
    for (int i = 0; i < 4; i++) {
      const int r = srow + 64 * i;
      gload16(Bt + (size_t)(bcol + r) * Kt + k0 + ((sslot ^ swz8(r)) * 8),
              Bb + w * 1024 + i * 8192);
    }
  };

  f32x4 acc[4][4] = {};

  stage(0, smem);

  const int ntile = Kt >> 6;
  for (int t = 0; t < ntile; t++) {
    const int cur = t & 1;
    unsigned char* Ab = smem + cur * 49152;
    unsigned char* Bb = Ab + 16384;

    __builtin_amdgcn_s_barrier();
    if (t + 1 < ntile) {
      stage((t + 1) << 6, smem + (cur ^ 1) * 49152);
      asm volatile("s_waitcnt vmcnt(6)");
    } else {
      asm volatile("s_waitcnt vmcnt(0)");
    }
    __builtin_amdgcn_sched_barrier(0);
    __builtin_amdgcn_s_barrier();

    bf16x8 af[4][2], bfv[4][2];
    #pragma unroll
    for (int mt = 0; mt < 4; mt++) {
      const int r = wm * 64 + mt * 16 + lrow;
      #pragma unroll
      for (int kk = 0; kk < 2; kk++)
        af[mt][kk] = *(const bf16x8*)(Ab + r * 128 + (((kk * 4 + lk) ^ swz8(r)) * 16));
    }
    #pragma unroll
    for (int nt = 0; nt < 4; nt++) {
      const int r = wn * 64 + nt * 16 + lrow;
      #pragma unroll
      for (int kk = 0; kk < 2; kk++)
        bfv[nt][kk] = *(const bf16x8*)(Bb + r * 128 + (((kk * 4 + lk) ^ swz8(r)) * 16));
    }
    __builtin_amdgcn_s_setprio(1);
    #pragma unroll
    for (int mt = 0; mt < 4; mt++)
      #pragma unroll
      for (int nt = 0; nt < 4; nt++) {
        acc[mt][nt] = __builtin_amdgcn_mfma_f32_16x16x32_bf16(af[mt][0], bfv[nt][0], acc[mt][nt], 0, 0, 0);
        acc[mt][nt] = __builtin_amdgcn_mfma_f32_16x16x32_bf16(af[mt][1], bfv[nt][1], acc[mt][nt], 0, 0, 0);
      }
    __builtin_amdgcn_s_setprio(0);
  }

  #pragma unroll
  for (int nt = 0; nt < 4; nt++) {
    const long col = bcol + wn * 64 + nt * 16 + lrow;
    const float bv = bias[col];
    #pragma unroll
    for (int mt = 0; mt < 4; mt++) {
      #pragma unroll
      for (int rr = 0; rr < 4; rr++) {
        const long row = brow + wm * 64 + mt * 16 + lk * 4 + rr;
        const float v = acc[mt][nt][rr] + bv;
        if (BF16_OUT)
          ((unsigned short*)Cout)[row * Nt + col] = f2bf(v);
        else
          ((float*)Cout)[row * Nt + col] = v;
      }
    }
  }
}

// ---------------- flash attention, swapped-QK^T, KVBLK=128, 256-row blocks ----------------
// (round-15 verified form, unchanged)
__global__ __launch_bounds__(512, 2)
void attn_fwd2(const unsigned short* __restrict__ QKV,
               unsigned short* __restrict__ Out) {
  __shared__ __align__(128) unsigned char smem[65536]; // 2 x (16K K + 16K VT)
  const int tid  = threadIdx.x;
  const int w    = tid >> 6;
  const int lane = tid & 63;
  const int li = lane & 31, hi = lane >> 5;
  const int bh = blockIdx.x;
  const int b  = bh >> 4, h = bh & 15;
  const int yy = (int)blockIdx.y;
  const int j  = (yy & 1) ? (yy >> 1) : (7 - (yy >> 1));  // 7,0,6,1,5,2,4,3
  const int wq = j * 256 + w * 32;
  const int qrow = wq + li;

  // Q as B-fragments: lane holds Q[q=li][d = ks*16 + hi*8 + j]
  bf16x8 qf[4];
  {
    const unsigned short* qp = QKV + (size_t)(b * Sn + qrow) * D3 + h * HD + hi * 8;
    #pragma unroll
    for (int ks = 0; ks < 4; ks++) qf[ks] = *(const bf16x8*)(qp + ks * 16);
  }

  f32x16 o0 = {}, o1 = {};
  float m = -3.0e38f, lsum = 0.f;
  const float cexp = 0.18033688011112042f;  // (1/8) * log2(e)

  // K stage: wave w stages rows [16w,16w+16) of the 128-row tile (2 gload16)
  auto kstage = [&](int kb, unsigned char* Kb) {
    #pragma unroll
    for (int i = 0; i < 2; i++) {
      const int r    = w * 16 + i * 8 + (lane >> 3);
      const int slot = (lane & 7) ^ swz8(r);
      gload16(QKV + (size_t)(b * Sn + kb + r) * D3 + Dn + h * HD + slot * 8,
              Kb + w * 2048 + i * 1024);
    }
  };
  const int vkv8 = tid >> 3;          // 0..63
  const int vd0  = (tid & 7) * 8;
  auto vload = [&](int kb, int i) -> bf16x8 {
    return *(const bf16x8*)(QKV + (size_t)(b * Sn + kb + i * 64 + vkv8) * D3 + 2 * Dn + h * HD + vd0);
  };
  auto vwrite = [&](bf16x8 vv, int i, unsigned char* Vb) {
    const int kv = i * 64 + vkv8;
    #pragma unroll
    for (int jj2 = 0; jj2 < 8; jj2++) {
      const int d  = vd0 + jj2;
      const int vs = (d ^ (d >> 3)) & 15;
      *(unsigned short*)(Vb + d * 256 + (((kv >> 3) ^ vs) << 4) + (kv & 7) * 2) = (unsigned short)vv[jj2];
    }
  };

  // one 64-kv online-softmax sub-step (s = 0 or 1 within the 128-kv tile)
  auto substep = [&](int s, int kb, const unsigned char* Kb, const unsigned char* Vb) {
    f32x16 s0 = {}, s1 = {};
    const int r0 = s * 64 + li, r1 = s * 64 + 32 + li;
    __builtin_amdgcn_s_setprio(1);
    #pragma unroll
    for (int ks = 0; ks < 4; ks++) {
      const int slot = ks * 2 + hi;
      const bf16x8 k0 = *(const bf16x8*)(Kb + r0 * 128 + ((slot ^ swz8(r0)) * 16));
      const bf16x8 k1 = *(const bf16x8*)(Kb + r1 * 128 + ((slot ^ swz8(r1)) * 16));
      s0 = __builtin_amdgcn_mfma_f32_32x32x16_bf16(k0, qf[ks], s0, 0, 0, 0);
      s1 = __builtin_amdgcn_mfma_f32_32x32x16_bf16(k1, qf[ks], s1, 0, 0, 0);
    }
    __builtin_amdgcn_s_setprio(0);
    const int kbase = kb + s * 64;
    if (kbase + 63 > wq) {   // diagonal tile: mask
      #pragma unroll
      for (int r = 0; r < 16; r++) {
        const int kvl = (r & 3) + 8 * (r >> 2) + 4 * hi;
        if (kbase + kvl > qrow)      s0[r] = -3.0e38f;
        if (kbase + 32 + kvl > qrow) s1[r] = -3.0e38f;
      }
    }
    // tree row-max (depth ~5)
    float t8[8];
    #pragma unroll
    for (int r = 0; r < 8; r++)
      t8[r] = fmaxf(fmaxf(s0[r], s0[r + 8]), fmaxf(s1[r], s1[r + 8]));
    float tmax = fmaxf(fmaxf(fmaxf(t8[0], t8[1]), fmaxf(t8[2], t8[3])),
                       fmaxf(fmaxf(t8[4], t8[5]), fmaxf(t8[6], t8[7])));
    tmax = fmaxf(tmax, __shfl_xor(tmax, 32));
    if (__any(tmax > m + 44.0f)) {   // defer-max
      const float mn   = fmaxf(m, tmax);
      const float corr = vexp2((m - mn) * cexp);
      m = mn;
      lsum *= corr;
      #pragma unroll
      for (int r = 0; r < 16; r++) {
        const float cr = lanepull(corr, (r & 3) + 8 * (r >> 2) + 4 * hi);
        o0[r] *= cr; o1[r] *= cr;
      }
    }
    const float mc = m * cexp;
    f32x16 p0, p1;
    float psa = 0.f, psb = 0.f, psc = 0.f, psd = 0.f;
    #pragma unroll
    for (int r = 0; r < 16; r += 4) {
      p0[r] = vexp2(fmaf(s0[r], cexp, -mc));         psa += p0[r];
      p0[r + 1] = vexp2(fmaf(s0[r + 1], cexp, -mc)); psb += p0[r + 1];
      p0[r + 2] = vexp2(fmaf(s0[r + 2], cexp, -mc)); psc += p0[r + 2];
      p0[r + 3] = vexp2(fmaf(s0[r + 3], cexp, -mc)); psd += p0[r + 3];
    }
    #pragma unroll
    for (int r = 0; r < 16; r += 4) {
      p1[r] = vexp2(fmaf(s1[r], cexp, -mc));         psa += p1[r];
      p1[r + 1] = vexp2(fmaf(s1[r + 1], cexp, -mc)); psb += p1[r + 1];
      p1[r + 2] = vexp2(fmaf(s1[r + 2], cexp, -mc)); psc += p1[r + 2];
      p1[r + 3] = vexp2(fmaf(s1[r + 3], cexp, -mc)); psd += p1[r + 3];
    }
    lsum += (psa + psb) + (psc + psd);

    // P -> bf16 A-fragments (in-register, partner exchange)
    auto mk_pa = [&](const f32x16& pp, int base) -> bf16x8 {
      const unsigned a0 = cvtpk(pp[base + 0], pp[base + 1]);
      const unsigned a1 = cvtpk(pp[base + 2], pp[base + 3]);
      const unsigned b0 = cvtpk(pp[base + 4], pp[base + 5]);
      const unsigned b1 = cvtpk(pp[base + 6], pp[base + 7]);
      const unsigned xa0 = __shfl_xor(a0, 32), xa1 = __shfl_xor(a1, 32);
      const unsigned xb0 = __shfl_xor(b0, 32), xb1 = __shfl_xor(b1, 32);
      union { unsigned u[4]; bf16x8 v; } pu;
      pu.u[0] = hi ? xb0 : a0;
      pu.u[1] = hi ? xb1 : a1;
      pu.u[2] = hi ? b0  : xa0;
      pu.u[3] = hi ? b1  : xa1;
      return pu.v;
    };
    bf16x8 pa[4];
    pa[0] = mk_pa(p0, 0); pa[1] = mk_pa(p0, 8);
    pa[2] = mk_pa(p1, 0); pa[3] = mk_pa(p1, 8);

    // O += P V   (VT rows, 16-slot swizzle)
    const int vs0 = (li ^ (li >> 3)) & 15;
    const int vs1 = ((32 + li) ^ ((32 + li) >> 3)) & 15;
    __builtin_amdgcn_s_setprio(1);
    #pragma unroll
    for (int k16 = 0; k16 < 4; k16++) {
      const int slot = s * 8 + k16 * 2 + hi;
      const bf16x8 vb0 = *(const bf16x8*)(Vb + li * 256 + ((slot ^ vs0) << 4));
      const bf16x8 vb1 = *(const bf16x8*)(Vb + (32 + li) * 256 + ((slot ^ vs1) << 4));
      o0 = __builtin_amdgcn_mfma_f32_32x32x16_bf16(pa[k16], vb0, o0, 0, 0, 0);
      o1 = __builtin_amdgcn_mfma_f32_32x32x16_bf16(pa[k16], vb1, o1, 0, 0, 0);
    }
    __builtin_amdgcn_s_setprio(0);
  };

  // prologue: stage tile 0 (vwrite's reg dependency drains vmcnt)
  kstage(0, smem);
  {
    bf16x8 va = vload(0, 0), vb = vload(0, 1);
    vwrite(va, 0, smem + 16384);
    vwrite(vb, 1, smem + 16384);
  }
  asm volatile("s_waitcnt lgkmcnt(0)");
  __builtin_amdgcn_sched_barrier(0);

  const int nt = 2 * j + 2;   // 128-kv tiles needed by the block's last q-row
  for (int t = 0; t < nt; t++) {
    const int kb  = t << 7;
    const int cur = t & 1;
    unsigned char* Kb = smem + cur * 32768;
    unsigned char* Vb = Kb + 16384;
    const bool pre = (t + 1 < nt);
    bf16x8 vna, vnb;

    // single barrier: retires t-1 readers; t's data already drained+visible
    __builtin_amdgcn_s_barrier();
    if (pre) {
      kstage(kb + 128, smem + (cur ^ 1) * 32768);   // K(t+1) -> LDS (async)
      vna = vload(kb + 128, 0);                     // V(t+1) -> regs (async)
      vnb = vload(kb + 128, 1);
    }

    if (kb <= wq + 31) {
      substep(0, kb, Kb, Vb);
      if (kb + 64 <= wq + 31) substep(1, kb, Kb, Vb);
    }

    if (pre) {
      unsigned char* Vn = smem + (cur ^ 1) * 32768 + 16384;
      vwrite(vna, 0, Vn);    // implicit vmcnt wait: drains K(t+1)+V(t+1)
      vwrite(vnb, 1, Vn);
    }
    asm volatile("s_waitcnt lgkmcnt(0)");
    __builtin_amdgcn_sched_barrier(0);
  }

  // ---- epilogue: O / l, merged-head store ----
  const float lt = lsum + __shfl_xor(lsum, 32);
  const float rl = __builtin_amdgcn_rcpf(lt);
  #pragma unroll
  for (int r = 0; r < 16; r++) {
    const int q = (r & 3) + 8 * (r >> 2) + 4 * hi;
    const float rr = lanepull(rl, q);
    unsigned short* op = Out + (size_t)(b * Sn + wq + q) * Dn + h * HD;
    op[li]      = f2bf(o0[r] * rr);
    op[32 + li] = f2bf(o1[r] * rr);
  }
}

// ---------------- tail: string_len -> float ----------------
__global__ void copy_len(const int* __restrict__ slen, float* __restrict__ dst, int n) {
  const int i = threadIdx.x;
  if (i < n) dst[i] = (float)slen[i];
}

extern "C" void kernel_launch(void* const* d_in, const int* in_sizes, int n_in,
                              void* d_out, int out_size, void* d_ws, size_t ws_size,
                              hipStream_t stream) {
  const float* X    = (const float*)d_in[0];
  const int*   slen = (const int*)d_in[1];
  const float* Wqkv = (const float*)d_in[2];
  const float* bqkv = (const float*)d_in[3];
  const float* Wo   = (const float*)d_in[4];
  const float* bo   = (const float*)d_in[5];
  float* out = (float*)d_out;

  char* ws = (char*)d_ws;
  unsigned short* Xb    = (unsigned short*)ws;
  unsigned short* Wtq   = (unsigned short*)(ws + 16777216);
  unsigned short* Wto   = (unsigned short*)(ws + 16777216 + 6291456);
  unsigned short* QKVb  = (unsigned short*)(ws + 16777216 + 6291456 + 2097152);
  unsigned short* Attnb = Xb;

  cvt_f32_bf16<<<dim3(8192), dim3(256), 0, stream>>>(X, Xb, Mrows * Dn);
  transpose_cvt<<<dim3(96, 32), dim3(32, 8), 0, stream>>>(Wqkv, Wtq, Dn, D3);
  transpose_cvt<<<dim3(32, 32), dim3(32, 8), 0, stream>>>(Wo, Wto, Dn, Dn);

  gemm_256<true><<<dim3(32, 12), dim3(512), 0, stream>>>(Xb, Wtq, bqkv, (void*)QKVb, D3, Dn);
  attn_fwd2<<<dim3(64, 8), dim3(512), 0, stream>>>(QKVb, Attnb);
  gemm_bt2<false><<<dim3(64, 4), dim3(512), 0, stream>>>(Attnb, Wto, bo, d_out, Dn, Dn);
  copy_len<<<dim3(1), dim3(64), 0, stream>>>(slen, out + (size_t)Mrows * Dn, Bn);
}

// Round 18
// 177.622 us; speedup vs baseline: 1.1124x; 1.1124x over previous
//
#include <hip/hip_runtime.h>
#include <stdint.h>

typedef __attribute__((ext_vector_type(8))) short bf16x8;
typedef __attribute__((ext_vector_type(4))) float f32x4;
typedef __attribute__((ext_vector_type(16))) float f32x16;
typedef __attribute__((ext_vector_type(4))) unsigned short u16x4;

static constexpr int Bn = 4, Sn = 2048, Dn = 1024, Hn = 16, HD = 64;
static constexpr int Mrows = Bn * Sn;   // 8192
static constexpr int D3 = 3 * Dn;       // 3072

__device__ __forceinline__ unsigned short f2bf(float f) {
  unsigned int u = __float_as_uint(f);
  u += 0x7FFF + ((u >> 16) & 1);
  return (unsigned short)(u >> 16);
}

__device__ __forceinline__ void gload16(const void* gptr, void* lptr) {
  __builtin_amdgcn_global_load_lds(
      (__attribute__((address_space(1))) void*)gptr,
      (__attribute__((address_space(3))) void*)lptr, 16, 0, 0);
}

__device__ __forceinline__ int swz8(int r) { return (r ^ (r >> 3)) & 7; }

__device__ __forceinline__ float vexp2(float x) {
#if __has_builtin(__builtin_amdgcn_exp2f)
  return __builtin_amdgcn_exp2f(x);
#else
  return exp2f(x);
#endif
}

__device__ __forceinline__ unsigned cvtpk(float lo, float hi) {
  unsigned r;
  asm("v_cvt_pk_bf16_f32 %0, %1, %2" : "=v"(r) : "v"(lo), "v"(hi));
  return r;
}

__device__ __forceinline__ float lanepull(float v, int srclane) {
  return __int_as_float(__builtin_amdgcn_ds_bpermute(srclane * 4, __float_as_int(v)));
}

// ---------------- elementwise f32 -> bf16 ----------------
__global__ void cvt_f32_bf16(const float* __restrict__ in,
                             unsigned short* __restrict__ out, int n) {
  int i = (blockIdx.x * blockDim.x + threadIdx.x) * 4;
  if (i < n) {
    const float4 v = *(const float4*)(in + i);
    u16x4 o;
    o.x = f2bf(v.x); o.y = f2bf(v.y); o.z = f2bf(v.z); o.w = f2bf(v.w);
    *(u16x4*)(out + i) = o;
  }
}

// ---------------- W [K][N] f32 -> W^T [N][K] bf16 ----------------
__global__ void transpose_cvt(const float* __restrict__ W,
                              unsigned short* __restrict__ Wt, int K, int N) {
  __shared__ float tile[32][33];
  const int n0 = blockIdx.x * 32, k0 = blockIdx.y * 32;
  const int tx = threadIdx.x, ty = threadIdx.y;   // block (32,8)
  #pragma unroll
  for (int j = 0; j < 4; j++)
    tile[ty + 8 * j][tx] = W[(size_t)(k0 + ty + 8 * j) * N + n0 + tx];
  __syncthreads();
  #pragma unroll
  for (int j = 0; j < 4; j++)
    Wt[(size_t)(n0 + ty + 8 * j) * K + k0 + tx] = f2bf(tile[tx][ty + 8 * j]);
}

// ---------------- 128x256 bf16 GEMM (bt2, round-13 proven) ----------------
template<bool BF16_OUT>
__global__ __launch_bounds__(512, 1)
void gemm_bt2(const unsigned short* __restrict__ A,
              const unsigned short* __restrict__ Bt,
              const float* __restrict__ bias,
              void* __restrict__ Cout, int Nt, int Kt) {
  __shared__ __align__(128) unsigned char smem[98304];  // 2 x (A 16K + B 32K)
  const int tid = threadIdx.x;
  const int w = tid >> 6, lane = tid & 63;
  const int wm = w >> 2, wn = w & 3;
  const int lrow = lane & 15, lk = lane >> 4;
  const long brow = (long)blockIdx.x * 128;
  const long bcol = (long)blockIdx.y * 256;

  const int srow = tid >> 3;    // 0..63
  const int sslot = tid & 7;

  auto stage = [&](int k0, unsigned char* buf) {   // 6 gloads: 2 A + 4 B
    unsigned char* Ab = buf;
    unsigned char* Bb = buf + 16384;
    #pragma unroll
    for (int i = 0; i < 2; i++) {
      const int r = srow + 64 * i;
      gload16(A + (size_t)(brow + r) * Kt + k0 + ((sslot ^ swz8(r)) * 8),
              Ab + w * 1024 + i * 8192);
    }
    #pragma unroll
    for (int i = 0; i < 4; i++) {
      const int r = srow + 64 * i;
      gload16(Bt + (size_t)(bcol + r) * Kt + k0 + ((sslot ^ swz8(r)) * 8),
              Bb + w * 1024 + i * 8192);
    }
  };

  f32x4 acc[4][4] = {};

  stage(0, smem);

  const int ntile = Kt >> 6;
  for (int t = 0; t < ntile; t++) {
    const int cur = t & 1;
    unsigned char* Ab = smem + cur * 49152;
    unsigned char* Bb = Ab + 16384;

    __builtin_amdgcn_s_barrier();
    if (t + 1 < ntile) {
      stage((t + 1) << 6, smem + (cur ^ 1) * 49152);
      asm volatile("s_waitcnt vmcnt(6)");
    } else {
      asm volatile("s_waitcnt vmcnt(0)");
    }
    __builtin_amdgcn_sched_barrier(0);
    __builtin_amdgcn_s_barrier();

    bf16x8 af[4][2], bfv[4][2];
    #pragma unroll
    for (int mt = 0; mt < 4; mt++) {
      const int r = wm * 64 + mt * 16 + lrow;
      #pragma unroll
      for (int kk = 0; kk < 2; kk++)
        af[mt][kk] = *(const bf16x8*)(Ab + r * 128 + (((kk * 4 + lk) ^ swz8(r)) * 16));
    }
    #pragma unroll
    for (int nt = 0; nt < 4; nt++) {
      const int r = wn * 64 + nt * 16 + lrow;
      #pragma unroll
      for (int kk = 0; kk < 2; kk++)
        bfv[nt][kk] = *(const bf16x8*)(Bb + r * 128 + (((kk * 4 + lk) ^ swz8(r)) * 16));
    }
    __builtin_amdgcn_s_setprio(1);
    #pragma unroll
    for (int mt = 0; mt < 4; mt++)
      #pragma unroll
      for (int nt = 0; nt < 4; nt++) {
        acc[mt][nt] = __builtin_amdgcn_mfma_f32_16x16x32_bf16(af[mt][0], bfv[nt][0], acc[mt][nt], 0, 0, 0);
        acc[mt][nt] = __builtin_amdgcn_mfma_f32_16x16x32_bf16(af[mt][1], bfv[nt][1], acc[mt][nt], 0, 0, 0);
      }
    __builtin_amdgcn_s_setprio(0);
  }

  #pragma unroll
  for (int nt = 0; nt < 4; nt++) {
    const long col = bcol + wn * 64 + nt * 16 + lrow;
    const float bv = bias[col];
    #pragma unroll
    for (int mt = 0; mt < 4; mt++) {
      #pragma unroll
      for (int rr = 0; rr < 4; rr++) {
        const long row = brow + wm * 64 + mt * 16 + lk * 4 + rr;
        const float v = acc[mt][nt][rr] + bv;
        if (BF16_OUT)
          ((unsigned short*)Cout)[row * Nt + col] = f2bf(v);
        else
          ((float*)Cout)[row * Nt + col] = v;
      }
    }
  }
}

// ---------------- flash attention: sequential-pair balanced schedule ----------------
// Block = (bh, p): owns q-tiles HEAVY=(7-p)*256 rows and LIGHT=p*256 rows.
// Each wave processes one 32-row heavy subtile AND one light subtile
// SEQUENTIALLY over ONE shared KV stream -> per-block work = 18 tile-units
// for every p (uniform by construction; fixes r15's 33%-active CU idling).
// Grid (64,4)=256 blocks = 1/CU; same-bh pairs on one XCD (id%8=bh%8).
// KV tile = 128 rows, double-buffered 64 KB LDS, one barrier/iter
// (loop-bottom vwrite dependency + lgkmcnt(0) drains; r13-proven form).
// K LDS: [128][64] bf16, swz8 16B-slot swizzle, gload_lds staged.
// V LDS: V^T [64 d][128 kv], (d^(d>>3))&15 slot swizzle, reg-staged.
// Dual state ~190 VGPR peak; launch_bounds(512,1) -> cap 256 (no r9 spill).
__global__ __launch_bounds__(512, 1)
void attn_pair(const unsigned short* __restrict__ QKV,
               unsigned short* __restrict__ Out) {
  __shared__ __align__(128) unsigned char smem[65536]; // 2 x (16K K + 16K VT)
  const int tid  = threadIdx.x;
  const int w    = tid >> 6;
  const int lane = tid & 63;
  const int li = lane & 31, hi = lane >> 5;
  const int bh = blockIdx.x;
  const int b  = bh >> 4, h = bh & 15;
  const int p  = blockIdx.y;                 // pair index 0..3
  const int wqh = (7 - p) * 256 + w * 32;    // heavy subtile base
  const int wql = p * 256 + w * 32;          // light subtile base

  const float cexp = 0.18033688011112042f;   // (1/8) * log2(e)

  // Q fragments for both subtiles
  bf16x8 qfh[4], qfl[4];
  {
    const unsigned short* qp = QKV + (size_t)(b * Sn + wqh + li) * D3 + h * HD + hi * 8;
    #pragma unroll
    for (int ks = 0; ks < 4; ks++) qfh[ks] = *(const bf16x8*)(qp + ks * 16);
  }
  {
    const unsigned short* qp = QKV + (size_t)(b * Sn + wql + li) * D3 + h * HD + hi * 8;
    #pragma unroll
    for (int ks = 0; ks < 4; ks++) qfl[ks] = *(const bf16x8*)(qp + ks * 16);
  }

  f32x16 o0h = {}, o1h = {}, o0l = {}, o1l = {};
  float mh = -3.0e38f, lsh = 0.f, ml = -3.0e38f, lsl = 0.f;

  // K stage: wave w stages rows [16w,16w+16) of the 128-row tile (2 gload16)
  auto kstage = [&](int kb, unsigned char* Kb) {
    #pragma unroll
    for (int i = 0; i < 2; i++) {
      const int r    = w * 16 + i * 8 + (lane >> 3);
      const int slot = (lane & 7) ^ swz8(r);
      gload16(QKV + (size_t)(b * Sn + kb + r) * D3 + Dn + h * HD + slot * 8,
              Kb + w * 2048 + i * 1024);
    }
  };
  const int vkv8 = tid >> 3;          // 0..63
  const int vd0  = (tid & 7) * 8;
  auto vload = [&](int kb, int i) -> bf16x8 {
    return *(const bf16x8*)(QKV + (size_t)(b * Sn + kb + i * 64 + vkv8) * D3 + 2 * Dn + h * HD + vd0);
  };
  auto vwrite = [&](bf16x8 vv, int i, unsigned char* Vb) {
    const int kv = i * 64 + vkv8;
    #pragma unroll
    for (int jj = 0; jj < 8; jj++) {
      const int d  = vd0 + jj;
      const int vs = (d ^ (d >> 3)) & 15;
      *(unsigned short*)(Vb + d * 256 + (((kv >> 3) ^ vs) << 4) + (kv & 7) * 2) = (unsigned short)vv[jj];
    }
  };

  // one 64-kv online-softmax sub-step for state (qf,o0,o1,m,ls) at q-base wqX
  auto substep = [&](int s, int kb, const unsigned char* Kb, const unsigned char* Vb,
                     int wqX, bf16x8 (&qf)[4], f32x16& o0, f32x16& o1,
                     float& m, float& ls) {
    const int qrowX = wqX + li;
    f32x16 s0 = {}, s1 = {};
    const int r0 = s * 64 + li, r1 = s * 64 + 32 + li;
    __builtin_amdgcn_s_setprio(1);
    #pragma unroll
    for (int ks = 0; ks < 4; ks++) {
      const int slot = ks * 2 + hi;
      const bf16x8 k0 = *(const bf16x8*)(Kb + r0 * 128 + ((slot ^ swz8(r0)) * 16));
      const bf16x8 k1 = *(const bf16x8*)(Kb + r1 * 128 + ((slot ^ swz8(r1)) * 16));
      s0 = __builtin_amdgcn_mfma_f32_32x32x16_bf16(k0, qf[ks], s0, 0, 0, 0);
      s1 = __builtin_amdgcn_mfma_f32_32x32x16_bf16(k1, qf[ks], s1, 0, 0, 0);
    }
    __builtin_amdgcn_s_setprio(0);
    const int kbase = kb + s * 64;
    if (kbase + 63 > wqX) {   // diagonal tile: mask
      #pragma unroll
      for (int r = 0; r < 16; r++) {
        const int kvl = (r & 3) + 8 * (r >> 2) + 4 * hi;
        if (kbase + kvl > qrowX)      s0[r] = -3.0e38f;
        if (kbase + 32 + kvl > qrowX) s1[r] = -3.0e38f;
      }
    }
    // tree row-max
    float t8[8];
    #pragma unroll
    for (int r = 0; r < 8; r++)
      t8[r] = fmaxf(fmaxf(s0[r], s0[r + 8]), fmaxf(s1[r], s1[r + 8]));
    float tmax = fmaxf(fmaxf(fmaxf(t8[0], t8[1]), fmaxf(t8[2], t8[3])),
                       fmaxf(fmaxf(t8[4], t8[5]), fmaxf(t8[6], t8[7])));
    tmax = fmaxf(tmax, __shfl_xor(tmax, 32));
    if (__any(tmax > m + 44.0f)) {   // defer-max
      const float mn   = fmaxf(m, tmax);
      const float corr = vexp2((m - mn) * cexp);
      m = mn;
      ls *= corr;
      #pragma unroll
      for (int r = 0; r < 16; r++) {
        const float cr = lanepull(corr, (r & 3) + 8 * (r >> 2) + 4 * hi);
        o0[r] *= cr; o1[r] *= cr;
      }
    }
    const float mc = m * cexp;
    f32x16 p0, p1;
    float psa = 0.f, psb = 0.f, psc = 0.f, psd = 0.f;
    #pragma unroll
    for (int r = 0; r < 16; r += 4) {
      p0[r] = vexp2(fmaf(s0[r], cexp, -mc));         psa += p0[r];
      p0[r + 1] = vexp2(fmaf(s0[r + 1], cexp, -mc)); psb += p0[r + 1];
      p0[r + 2] = vexp2(fmaf(s0[r + 2], cexp, -mc)); psc += p0[r + 2];
      p0[r + 3] = vexp2(fmaf(s0[r + 3], cexp, -mc)); psd += p0[r + 3];
    }
    #pragma unroll
    for (int r = 0; r < 16; r += 4) {
      p1[r] = vexp2(fmaf(s1[r], cexp, -mc));         psa += p1[r];
      p1[r + 1] = vexp2(fmaf(s1[r + 1], cexp, -mc)); psb += p1[r + 1];
      p1[r + 2] = vexp2(fmaf(s1[r + 2], cexp, -mc)); psc += p1[r + 2];
      p1[r + 3] = vexp2(fmaf(s1[r + 3], cexp, -mc)); psd += p1[r + 3];
    }
    ls += (psa + psb) + (psc + psd);

    // P -> bf16 A-fragments (in-register, partner exchange)
    auto mk_pa = [&](const f32x16& pp, int base) -> bf16x8 {
      const unsigned a0 = cvtpk(pp[base + 0], pp[base + 1]);
      const unsigned a1 = cvtpk(pp[base + 2], pp[base + 3]);
      const unsigned b0 = cvtpk(pp[base + 4], pp[base + 5]);
      const unsigned b1 = cvtpk(pp[base + 6], pp[base + 7]);
      const unsigned xa0 = __shfl_xor(a0, 32), xa1 = __shfl_xor(a1, 32);
      const unsigned xb0 = __shfl_xor(b0, 32), xb1 = __shfl_xor(b1, 32);
      union { unsigned u[4]; bf16x8 v; } pu;
      pu.u[0] = hi ? xb0 : a0;
      pu.u[1] = hi ? xb1 : a1;
      pu.u[2] = hi ? b0  : xa0;
      pu.u[3] = hi ? b1  : xa1;
      return pu.v;
    };
    bf16x8 pa[4];
    pa[0] = mk_pa(p0, 0); pa[1] = mk_pa(p0, 8);
    pa[2] = mk_pa(p1, 0); pa[3] = mk_pa(p1, 8);

    // O += P V   (VT rows, 16-slot swizzle)
    const int vs0 = (li ^ (li >> 3)) & 15;
    const int vs1 = ((32 + li) ^ ((32 + li) >> 3)) & 15;
    __builtin_amdgcn_s_setprio(1);
    #pragma unroll
    for (int k16 = 0; k16 < 4; k16++) {
      const int slot = s * 8 + k16 * 2 + hi;
      const bf16x8 vb0 = *(const bf16x8*)(Vb + li * 256 + ((slot ^ vs0) << 4));
      const bf16x8 vb1 = *(const bf16x8*)(Vb + (32 + li) * 256 + ((slot ^ vs1) << 4));
      o0 = __builtin_amdgcn_mfma_f32_32x32x16_bf16(pa[k16], vb0, o0, 0, 0, 0);
      o1 = __builtin_amdgcn_mfma_f32_32x32x16_bf16(pa[k16], vb1, o1, 0, 0, 0);
    }
    __builtin_amdgcn_s_setprio(0);
  };

  // prologue: stage tile 0
  kstage(0, smem);
  {
    bf16x8 va = vload(0, 0), vb = vload(0, 1);
    vwrite(va, 0, smem + 16384);
    vwrite(vb, 1, smem + 16384);
  }
  asm volatile("s_waitcnt lgkmcnt(0)");
  __builtin_amdgcn_sched_barrier(0);

  const int nt = 16 - 2 * p;   // tiles needed by the heavy q-tile
  for (int t = 0; t < nt; t++) {
    const int kb  = t << 7;
    const int cur = t & 1;
    unsigned char* Kb = smem + cur * 32768;
    unsigned char* Vb = Kb + 16384;
    const bool pre = (t + 1 < nt);
    bf16x8 vna, vnb;

    __builtin_amdgcn_s_barrier();
    if (pre) {
      kstage(kb + 128, smem + (cur ^ 1) * 32768);
      vna = vload(kb + 128, 0);
      vnb = vload(kb + 128, 1);
    }

    // heavy subtile
    if (kb <= wqh + 31) {
      substep(0, kb, Kb, Vb, wqh, qfh, o0h, o1h, mh, lsh);
      if (kb + 64 <= wqh + 31) substep(1, kb, Kb, Vb, wqh, qfh, o0h, o1h, mh, lsh);
    }
    // light subtile (same KV stream)
    if (kb <= wql + 31) {
      substep(0, kb, Kb, Vb, wql, qfl, o0l, o1l, ml, lsl);
      if (kb + 64 <= wql + 31) substep(1, kb, Kb, Vb, wql, qfl, o0l, o1l, ml, lsl);
    }

    if (pre) {
      unsigned char* Vn = smem + (cur ^ 1) * 32768 + 16384;
      vwrite(vna, 0, Vn);    // implicit vmcnt wait drains K(t+1)+V(t+1)
      vwrite(vnb, 1, Vn);
    }
    asm volatile("s_waitcnt lgkmcnt(0)");
    __builtin_amdgcn_sched_barrier(0);
  }

  // ---- epilogue: both subtiles ----
  {
    const float lt = lsh + __shfl_xor(lsh, 32);
    const float rl = __builtin_amdgcn_rcpf(lt);
    #pragma unroll
    for (int r = 0; r < 16; r++) {
      const int q = (r & 3) + 8 * (r >> 2) + 4 * hi;
      const float rr = lanepull(rl, q);
      unsigned short* op = Out + (size_t)(b * Sn + wqh + q) * Dn + h * HD;
      op[li]      = f2bf(o0h[r] * rr);
      op[32 + li] = f2bf(o1h[r] * rr);
    }
  }
  {
    const float lt = lsl + __shfl_xor(lsl, 32);
    const float rl = __builtin_amdgcn_rcpf(lt);
    #pragma unroll
    for (int r = 0; r < 16; r++) {
      const int q = (r & 3) + 8 * (r >> 2) + 4 * hi;
      const float rr = lanepull(rl, q);
      unsigned short* op = Out + (size_t)(b * Sn + wql + q) * Dn + h * HD;
      op[li]      = f2bf(o0l[r] * rr);
      op[32 + li] = f2bf(o1l[r] * rr);
    }
  }
}

// ---------------- tail: string_len -> float ----------------
__global__ void copy_len(const int* __restrict__ slen, float* __restrict__ dst, int n) {
  const int i = threadIdx.x;
  if (i < n) dst[i] = (float)slen[i];
}

extern "C" void kernel_launch(void* const* d_in, const int* in_sizes, int n_in,
                              void* d_out, int out_size, void* d_ws, size_t ws_size,
                              hipStream_t stream) {
  const float* X    = (const float*)d_in[0];
  const int*   slen = (const int*)d_in[1];
  const float* Wqkv = (const float*)d_in[2];
  const float* bqkv = (const float*)d_in[3];
  const float* Wo   = (const float*)d_in[4];
  const float* bo   = (const float*)d_in[5];
  float* out = (float*)d_out;

  char* ws = (char*)d_ws;
  unsigned short* Xb    = (unsigned short*)ws;
  unsigned short* Wtq   = (unsigned short*)(ws + 16777216);
  unsigned short* Wto   = (unsigned short*)(ws + 16777216 + 6291456);
  unsigned short* QKVb  = (unsigned short*)(ws + 16777216 + 6291456 + 2097152);
  unsigned short* Attnb = Xb;

  cvt_f32_bf16<<<dim3(8192), dim3(256), 0, stream>>>(X, Xb, Mrows * Dn);
  transpose_cvt<<<dim3(96, 32), dim3(32, 8), 0, stream>>>(Wqkv, Wtq, Dn, D3);
  transpose_cvt<<<dim3(32, 32), dim3(32, 8), 0, stream>>>(Wo, Wto, Dn, Dn);

  gemm_bt2<true><<<dim3(64, 12), dim3(512), 0, stream>>>(Xb, Wtq, bqkv, (void*)QKVb, D3, Dn);
  attn_pair<<<dim3(64, 4), dim3(512), 0, stream>>>(QKVb, Attnb);
  gemm_bt2<false><<<dim3(64, 4), dim3(512), 0, stream>>>(Attnb, Wto, bo, d_out, Dn, Dn);
  copy_len<<<dim3(1), dim3(64), 0, stream>>>(slen, out + (size_t)Mrows * Dn, Bn);
}

// Round 19
// 158.364 us; speedup vs baseline: 1.2477x; 1.1216x over previous
//
#include <hip/hip_runtime.h>
#include <hip/hip_fp8.h>
#include <stdint.h>

typedef __attribute__((ext_vector_type(8))) short bf16x8;
typedef __attribute__((ext_vector_type(4))) float f32x4;
typedef __attribute__((ext_vector_type(16))) float f32x16;
typedef __attribute__((ext_vector_type(4))) unsigned short u16x4;

static constexpr int Bn = 4, Sn = 2048, Dn = 1024, Hn = 16, HD = 64;
static constexpr int Mrows = Bn * Sn;   // 8192
static constexpr int D3 = 3 * Dn;       // 3072

__device__ __forceinline__ unsigned short f2bf(float f) {
  unsigned int u = __float_as_uint(f);
  u += 0x7FFF + ((u >> 16) & 1);
  return (unsigned short)(u >> 16);
}

__device__ __forceinline__ unsigned char f2fp8(float f) {
  __hip_fp8_e4m3 v(f);
  return (unsigned char)v.__x;
}

__device__ __forceinline__ void gload16(const void* gptr, void* lptr) {
  __builtin_amdgcn_global_load_lds(
      (__attribute__((address_space(1))) void*)gptr,
      (__attribute__((address_space(3))) void*)lptr, 16, 0, 0);
}

__device__ __forceinline__ int swz8(int r) { return (r ^ (r >> 3)) & 7; }

__device__ __forceinline__ float vexp2(float x) {
#if __has_builtin(__builtin_amdgcn_exp2f)
  return __builtin_amdgcn_exp2f(x);
#else
  return exp2f(x);
#endif
}

__device__ __forceinline__ unsigned cvtpk(float lo, float hi) {
  unsigned r;
  asm("v_cvt_pk_bf16_f32 %0, %1, %2" : "=v"(r) : "v"(lo), "v"(hi));
  return r;
}

__device__ __forceinline__ float lanepull(float v, int srclane) {
  return __int_as_float(__builtin_amdgcn_ds_bpermute(srclane * 4, __float_as_int(v)));
}

// ---------------- elementwise f32 -> fp8 e4m3 ----------------
__global__ void cvt_f32_fp8(const float* __restrict__ in,
                            unsigned char* __restrict__ out, int n) {
  int i = (blockIdx.x * blockDim.x + threadIdx.x) * 4;
  if (i < n) {
    const float4 v = *(const float4*)(in + i);
    uchar4 o;
    o.x = f2fp8(v.x); o.y = f2fp8(v.y); o.z = f2fp8(v.z); o.w = f2fp8(v.w);
    *(uchar4*)(out + i) = o;
  }
}

// ---------------- W [K][N] f32 -> W^T [N][K] fp8 (scaled x64) ----------------
__global__ void transpose_cvt_fp8(const float* __restrict__ W,
                                  unsigned char* __restrict__ Wt, int K, int N) {
  __shared__ float tile[32][33];
  const int n0 = blockIdx.x * 32, k0 = blockIdx.y * 32;
  const int tx = threadIdx.x, ty = threadIdx.y;   // block (32,8)
  #pragma unroll
  for (int j = 0; j < 4; j++)
    tile[ty + 8 * j][tx] = W[(size_t)(k0 + ty + 8 * j) * N + n0 + tx];
  __syncthreads();
  #pragma unroll
  for (int j = 0; j < 4; j++)
    Wt[(size_t)(n0 + ty + 8 * j) * K + k0 + tx] = f2fp8(tile[tx][ty + 8 * j] * 64.0f);
}

// ---------------- W [K][N] f32 -> W^T [N][K] bf16 (for proj) ----------------
__global__ void transpose_cvt(const float* __restrict__ W,
                              unsigned short* __restrict__ Wt, int K, int N) {
  __shared__ float tile[32][33];
  const int n0 = blockIdx.x * 32, k0 = blockIdx.y * 32;
  const int tx = threadIdx.x, ty = threadIdx.y;   // block (32,8)
  #pragma unroll
  for (int j = 0; j < 4; j++)
    tile[ty + 8 * j][tx] = W[(size_t)(k0 + ty + 8 * j) * N + n0 + tx];
  __syncthreads();
  #pragma unroll
  for (int j = 0; j < 4; j++)
    Wt[(size_t)(n0 + ty + 8 * j) * K + k0 + tx] = f2bf(tile[tx][ty + 8 * j]);
}

// ---------------- 128x256 fp8 GEMM, BK=128: C = A[M,K] @ (64*Bt)[N,K]^T /64 + bias ----------------
// bt2 staging frame unchanged (128-B rows, swz8 16B-slot swizzle, 6 gloads,
// counted vmcnt(6), 2-barrier loop) but rows now hold 128 fp8 -> BK=128:
// iterations 16 -> 8 (half the barriers + staging), 64 MFMA/wave/iter via
// mfma_f32_16x16x32_fp8_fp8 (b64 frags: lane reads row lrow, k=kk*32+lk*8..+7;
// 16B-slot s16=kk*2+(lk>>1), byte = ((s16^swz8(r))<<4) + (lk&1)*8).
// Epilogue un-scales W's x64 (acc * 1/64) then adds bias; bf16 out.
__global__ __launch_bounds__(512, 1)
void gemm_fp8(const unsigned char* __restrict__ A,
              const unsigned char* __restrict__ Bt,
              const float* __restrict__ bias,
              unsigned short* __restrict__ Cout, int Nt, int Kt) {
  __shared__ __align__(128) unsigned char smem[98304];  // 2 x (A 16K + B 32K)
  const int tid = threadIdx.x;
  const int w = tid >> 6, lane = tid & 63;
  const int wm = w >> 2, wn = w & 3;
  const int lrow = lane & 15, lk = lane >> 4;
  const long brow = (long)blockIdx.x * 128;
  const long bcol = (long)blockIdx.y * 256;

  const int srow = tid >> 3;    // 0..63
  const int sslot = tid & 7;

  auto stage = [&](int k0, unsigned char* buf) {   // 6 gloads: 2 A + 4 B
    unsigned char* Ab = buf;
    unsigned char* Bb = buf + 16384;
    #pragma unroll
    for (int i = 0; i < 2; i++) {
      const int r = srow + 64 * i;
      gload16(A + (size_t)(brow + r) * Kt + k0 + ((sslot ^ swz8(r)) * 16),
              Ab + w * 1024 + i * 8192);
    }
    #pragma unroll
    for (int i = 0; i < 4; i++) {
      const int r = srow + 64 * i;
      gload16(Bt + (size_t)(bcol + r) * Kt + k0 + ((sslot ^ swz8(r)) * 16),
              Bb + w * 1024 + i * 8192);
    }
  };

  f32x4 acc[4][4] = {};

  stage(0, smem);

  const int ntile = Kt >> 7;          // BK = 128
  for (int t = 0; t < ntile; t++) {
    const int cur = t & 1;
    unsigned char* Ab = smem + cur * 49152;
    unsigned char* Bb = Ab + 16384;

    __builtin_amdgcn_s_barrier();     // retires t-1 readers of buf^1
    if (t + 1 < ntile) {
      stage((t + 1) << 7, smem + (cur ^ 1) * 49152);
      asm volatile("s_waitcnt vmcnt(6)");  // t's 6 loads done; t+1's in flight
    } else {
      asm volatile("s_waitcnt vmcnt(0)");
    }
    __builtin_amdgcn_sched_barrier(0);
    __builtin_amdgcn_s_barrier();     // buf t visible block-wide

    const int sub = (lk & 1) * 8;
    #pragma unroll
    for (int kk = 0; kk < 4; kk++) {
      const int s16 = kk * 2 + (lk >> 1);
      long av[4], bv[4];
      #pragma unroll
      for (int mt = 0; mt < 4; mt++) {
        const int r = wm * 64 + mt * 16 + lrow;
        av[mt] = *(const long*)(Ab + r * 128 + (((s16 ^ swz8(r)) << 4) + sub));
      }
      #pragma unroll
      for (int nt = 0; nt < 4; nt++) {
        const int r = wn * 64 + nt * 16 + lrow;
        bv[nt] = *(const long*)(Bb + r * 128 + (((s16 ^ swz8(r)) << 4) + sub));
      }
      __builtin_amdgcn_s_setprio(1);
      #pragma unroll
      for (int mt = 0; mt < 4; mt++)
        #pragma unroll
        for (int nt = 0; nt < 4; nt++)
          acc[mt][nt] = __builtin_amdgcn_mfma_f32_16x16x32_fp8_fp8(av[mt], bv[nt], acc[mt][nt], 0, 0, 0);
      __builtin_amdgcn_s_setprio(0);
    }
  }

  #pragma unroll
  for (int nt = 0; nt < 4; nt++) {
    const long col = bcol + wn * 64 + nt * 16 + lrow;
    const float bv2 = bias[col];
    #pragma unroll
    for (int mt = 0; mt < 4; mt++) {
      #pragma unroll
      for (int rr = 0; rr < 4; rr++) {
        const long row = brow + wm * 64 + mt * 16 + lk * 4 + rr;
        Cout[row * Nt + col] = f2bf(acc[mt][nt][rr] * 0.015625f + bv2);
      }
    }
  }
}

// ---------------- 128x256 bf16 GEMM (bt2, round-13 proven; proj only) ----------------
template<bool BF16_OUT>
__global__ __launch_bounds__(512, 1)
void gemm_bt2(const unsigned short* __restrict__ A,
              const unsigned short* __restrict__ Bt,
              const float* __restrict__ bias,
              void* __restrict__ Cout, int Nt, int Kt) {
  __shared__ __align__(128) unsigned char smem[98304];  // 2 x (A 16K + B 32K)
  const int tid = threadIdx.x;
  const int w = tid >> 6, lane = tid & 63;
  const int wm = w >> 2, wn = w & 3;
  const int lrow = lane & 15, lk = lane >> 4;
  const long brow = (long)blockIdx.x * 128;
  const long bcol = (long)blockIdx.y * 256;

  const int srow = tid >> 3;    // 0..63
  const int sslot = tid & 7;

  auto stage = [&](int k0, unsigned char* buf) {   // 6 gloads: 2 A + 4 B
    unsigned char* Ab = buf;
    unsigned char* Bb = buf + 16384;
    #pragma unroll
    for (int i = 0; i < 2; i++) {
      const int r = srow + 64 * i;
      gload16(A + (size_t)(brow + r) * Kt + k0 + ((sslot ^ swz8(r)) * 8),
              Ab + w * 1024 + i * 8192);
    }
    #pragma unroll
    for (int i = 0; i < 4; i++) {
      const int r = srow + 64 * i;
      gload16(Bt + (size_t)(bcol + r) * Kt + k0 + ((sslot ^ swz8(r)) * 8),
              Bb + w * 1024 + i * 8192);
    }
  };

  f32x4 acc[4][4] = {};

  stage(0, smem);

  const int ntile = Kt >> 6;
  for (int t = 0; t < ntile; t++) {
    const int cur = t & 1;
    unsigned char* Ab = smem + cur * 49152;
    unsigned char* Bb = Ab + 16384;

    __builtin_amdgcn_s_barrier();
    if (t + 1 < ntile) {
      stage((t + 1) << 6, smem + (cur ^ 1) * 49152);
      asm volatile("s_waitcnt vmcnt(6)");
    } else {
      asm volatile("s_waitcnt vmcnt(0)");
    }
    __builtin_amdgcn_sched_barrier(0);
    __builtin_amdgcn_s_barrier();

    bf16x8 af[4][2], bfv[4][2];
    #pragma unroll
    for (int mt = 0; mt < 4; mt++) {
      const int r = wm * 64 + mt * 16 + lrow;
      #pragma unroll
      for (int kk = 0; kk < 2; kk++)
        af[mt][kk] = *(const bf16x8*)(Ab + r * 128 + (((kk * 4 + lk) ^ swz8(r)) * 16));
    }
    #pragma unroll
    for (int nt = 0; nt < 4; nt++) {
      const int r = wn * 64 + nt * 16 + lrow;
      #pragma unroll
      for (int kk = 0; kk < 2; kk++)
        bfv[nt][kk] = *(const bf16x8*)(Bb + r * 128 + (((kk * 4 + lk) ^ swz8(r)) * 16));
    }
    __builtin_amdgcn_s_setprio(1);
    #pragma unroll
    for (int mt = 0; mt < 4; mt++)
      #pragma unroll
      for (int nt = 0; nt < 4; nt++) {
        acc[mt][nt] = __builtin_amdgcn_mfma_f32_16x16x32_bf16(af[mt][0], bfv[nt][0], acc[mt][nt], 0, 0, 0);
        acc[mt][nt] = __builtin_amdgcn_mfma_f32_16x16x32_bf16(af[mt][1], bfv[nt][1], acc[mt][nt], 0, 0, 0);
      }
    __builtin_amdgcn_s_setprio(0);
  }

  #pragma unroll
  for (int nt = 0; nt < 4; nt++) {
    const long col = bcol + wn * 64 + nt * 16 + lrow;
    const float bv = bias[col];
    #pragma unroll
    for (int mt = 0; mt < 4; mt++) {
      #pragma unroll
      for (int rr = 0; rr < 4; rr++) {
        const long row = brow + wm * 64 + mt * 16 + lk * 4 + rr;
        const float v = acc[mt][nt][rr] + bv;
        if (BF16_OUT)
          ((unsigned short*)Cout)[row * Nt + col] = f2bf(v);
        else
          ((float*)Cout)[row * Nt + col] = v;
      }
    }
  }
}

// ---------------- flash attention: sequential-pair balanced schedule ----------------
// (round-18 verified form, unchanged)
__global__ __launch_bounds__(512, 1)
void attn_pair(const unsigned short* __restrict__ QKV,
               unsigned short* __restrict__ Out) {
  __shared__ __align__(128) unsigned char smem[65536]; // 2 x (16K K + 16K VT)
  const int tid  = threadIdx.x;
  const int w    = tid >> 6;
  const int lane = tid & 63;
  const int li = lane & 31, hi = lane >> 5;
  const int bh = blockIdx.x;
  const int b  = bh >> 4, h = bh & 15;
  const int p  = blockIdx.y;                 // pair index 0..3
  const int wqh = (7 - p) * 256 + w * 32;    // heavy subtile base
  const int wql = p * 256 + w * 32;          // light subtile base

  const float cexp = 0.18033688011112042f;   // (1/8) * log2(e)

  bf16x8 qfh[4], qfl[4];
  {
    const unsigned short* qp = QKV + (size_t)(b * Sn + wqh + li) * D3 + h * HD + hi * 8;
    #pragma unroll
    for (int ks = 0; ks < 4; ks++) qfh[ks] = *(const bf16x8*)(qp + ks * 16);
  }
  {
    const unsigned short* qp = QKV + (size_t)(b * Sn + wql + li) * D3 + h * HD + hi * 8;
    #pragma unroll
    for (int ks = 0; ks < 4; ks++) qfl[ks] = *(const bf16x8*)(qp + ks * 16);
  }

  f32x16 o0h = {}, o1h = {}, o0l = {}, o1l = {};
  float mh = -3.0e38f, lsh = 0.f, ml = -3.0e38f, lsl = 0.f;

  auto kstage = [&](int kb, unsigned char* Kb) {
    #pragma unroll
    for (int i = 0; i < 2; i++) {
      const int r    = w * 16 + i * 8 + (lane >> 3);
      const int slot = (lane & 7) ^ swz8(r);
      gload16(QKV + (size_t)(b * Sn + kb + r) * D3 + Dn + h * HD + slot * 8,
              Kb + w * 2048 + i * 1024);
    }
  };
  const int vkv8 = tid >> 3;          // 0..63
  const int vd0  = (tid & 7) * 8;
  auto vload = [&](int kb, int i) -> bf16x8 {
    return *(const bf16x8*)(QKV + (size_t)(b * Sn + kb + i * 64 + vkv8) * D3 + 2 * Dn + h * HD + vd0);
  };
  auto vwrite = [&](bf16x8 vv, int i, unsigned char* Vb) {
    const int kv = i * 64 + vkv8;
    #pragma unroll
    for (int jj = 0; jj < 8; jj++) {
      const int d  = vd0 + jj;
      const int vs = (d ^ (d >> 3)) & 15;
      *(unsigned short*)(Vb + d * 256 + (((kv >> 3) ^ vs) << 4) + (kv & 7) * 2) = (unsigned short)vv[jj];
    }
  };

  auto substep = [&](int s, int kb, const unsigned char* Kb, const unsigned char* Vb,
                     int wqX, bf16x8 (&qf)[4], f32x16& o0, f32x16& o1,
                     float& m, float& ls) {
    const int qrowX = wqX + li;
    f32x16 s0 = {}, s1 = {};
    const int r0 = s * 64 + li, r1 = s * 64 + 32 + li;
    __builtin_amdgcn_s_setprio(1);
    #pragma unroll
    for (int ks = 0; ks < 4; ks++) {
      const int slot = ks * 2 + hi;
      const bf16x8 k0 = *(const bf16x8*)(Kb + r0 * 128 + ((slot ^ swz8(r0)) * 16));
      const bf16x8 k1 = *(const bf16x8*)(Kb + r1 * 128 + ((slot ^ swz8(r1)) * 16));
      s0 = __builtin_amdgcn_mfma_f32_32x32x16_bf16(k0, qf[ks], s0, 0, 0, 0);
      s1 = __builtin_amdgcn_mfma_f32_32x32x16_bf16(k1, qf[ks], s1, 0, 0, 0);
    }
    __builtin_amdgcn_s_setprio(0);
    const int kbase = kb + s * 64;
    if (kbase + 63 > wqX) {
      #pragma unroll
      for (int r = 0; r < 16; r++) {
        const int kvl = (r & 3) + 8 * (r >> 2) + 4 * hi;
        if (kbase + kvl > qrowX)      s0[r] = -3.0e38f;
        if (kbase + 32 + kvl > qrowX) s1[r] = -3.0e38f;
      }
    }
    float t8[8];
    #pragma unroll
    for (int r = 0; r < 8; r++)
      t8[r] = fmaxf(fmaxf(s0[r], s0[r + 8]), fmaxf(s1[r], s1[r + 8]));
    float tmax = fmaxf(fmaxf(fmaxf(t8[0], t8[1]), fmaxf(t8[2], t8[3])),
                       fmaxf(fmaxf(t8[4], t8[5]), fmaxf(t8[6], t8[7])));
    tmax = fmaxf(tmax, __shfl_xor(tmax, 32));
    if (__any(tmax > m + 44.0f)) {
      const float mn   = fmaxf(m, tmax);
      const float corr = vexp2((m - mn) * cexp);
      m = mn;
      ls *= corr;
      #pragma unroll
      for (int r = 0; r < 16; r++) {
        const float cr = lanepull(corr, (r & 3) + 8 * (r >> 2) + 4 * hi);
        o0[r] *= cr; o1[r] *= cr;
      }
    }
    const float mc = m * cexp;
    f32x16 p0, p1;
    float psa = 0.f, psb = 0.f, psc = 0.f, psd = 0.f;
    #pragma unroll
    for (int r = 0; r < 16; r += 4) {
      p0[r] = vexp2(fmaf(s0[r], cexp, -mc));         psa += p0[r];
      p0[r + 1] = vexp2(fmaf(s0[r + 1], cexp, -mc)); psb += p0[r + 1];
      p0[r + 2] = vexp2(fmaf(s0[r + 2], cexp, -mc)); psc += p0[r + 2];
      p0[r + 3] = vexp2(fmaf(s0[r + 3], cexp, -mc)); psd += p0[r + 3];
    }
    #pragma unroll
    for (int r = 0; r < 16; r += 4) {
      p1[r] = vexp2(fmaf(s1[r], cexp, -mc));         psa += p1[r];
      p1[r + 1] = vexp2(fmaf(s1[r + 1], cexp, -mc)); psb += p1[r + 1];
      p1[r + 2] = vexp2(fmaf(s1[r + 2], cexp, -mc)); psc += p1[r + 2];
      p1[r + 3] = vexp2(fmaf(s1[r + 3], cexp, -mc)); psd += p1[r + 3];
    }
    ls += (psa + psb) + (psc + psd);

    auto mk_pa = [&](const f32x16& pp, int base) -> bf16x8 {
      const unsigned a0 = cvtpk(pp[base + 0], pp[base + 1]);
      const unsigned a1 = cvtpk(pp[base + 2], pp[base + 3]);
      const unsigned b0 = cvtpk(pp[base + 4], pp[base + 5]);
      const unsigned b1 = cvtpk(pp[base + 6], pp[base + 7]);
      const unsigned xa0 = __shfl_xor(a0, 32), xa1 = __shfl_xor(a1, 32);
      const unsigned xb0 = __shfl_xor(b0, 32), xb1 = __shfl_xor(b1, 32);
      union { unsigned u[4]; bf16x8 v; } pu;
      pu.u[0] = hi ? xb0 : a0;
      pu.u[1] = hi ? xb1 : a1;
      pu.u[2] = hi ? b0  : xa0;
      pu.u[3] = hi ? b1  : xa1;
      return pu.v;
    };
    bf16x8 pa[4];
    pa[0] = mk_pa(p0, 0); pa[1] = mk_pa(p0, 8);
    pa[2] = mk_pa(p1, 0); pa[3] = mk_pa(p1, 8);

    const int vs0 = (li ^ (li >> 3)) & 15;
    const int vs1 = ((32 + li) ^ ((32 + li) >> 3)) & 15;
    __builtin_amdgcn_s_setprio(1);
    #pragma unroll
    for (int k16 = 0; k16 < 4; k16++) {
      const int slot = s * 8 + k16 * 2 + hi;
      const bf16x8 vb0 = *(const bf16x8*)(Vb + li * 256 + ((slot ^ vs0) << 4));
      const bf16x8 vb1 = *(const bf16x8*)(Vb + (32 + li) * 256 + ((slot ^ vs1) << 4));
      o0 = __builtin_amdgcn_mfma_f32_32x32x16_bf16(pa[k16], vb0, o0, 0, 0, 0);
      o1 = __builtin_amdgcn_mfma_f32_32x32x16_bf16(pa[k16], vb1, o1, 0, 0, 0);
    }
    __builtin_amdgcn_s_setprio(0);
  };

  kstage(0, smem);
  {
    bf16x8 va = vload(0, 0), vb = vload(0, 1);
    vwrite(va, 0, smem + 16384);
    vwrite(vb, 1, smem + 16384);
  }
  asm volatile("s_waitcnt lgkmcnt(0)");
  __builtin_amdgcn_sched_barrier(0);

  const int nt = 16 - 2 * p;   // tiles needed by the heavy q-tile
  for (int t = 0; t < nt; t++) {
    const int kb  = t << 7;
    const int cur = t & 1;
    unsigned char* Kb = smem + cur * 32768;
    unsigned char* Vb = Kb + 16384;
    const bool pre = (t + 1 < nt);
    bf16x8 vna, vnb;

    __builtin_amdgcn_s_barrier();
    if (pre) {
      kstage(kb + 128, smem + (cur ^ 1) * 32768);
      vna = vload(kb + 128, 0);
      vnb = vload(kb + 128, 1);
    }

    if (kb <= wqh + 31) {
      substep(0, kb, Kb, Vb, wqh, qfh, o0h, o1h, mh, lsh);
      if (kb + 64 <= wqh + 31) substep(1, kb, Kb, Vb, wqh, qfh, o0h, o1h, mh, lsh);
    }
    if (kb <= wql + 31) {
      substep(0, kb, Kb, Vb, wql, qfl, o0l, o1l, ml, lsl);
      if (kb + 64 <= wql + 31) substep(1, kb, Kb, Vb, wql, qfl, o0l, o1l, ml, lsl);
    }

    if (pre) {
      unsigned char* Vn = smem + (cur ^ 1) * 32768 + 16384;
      vwrite(vna, 0, Vn);
      vwrite(vnb, 1, Vn);
    }
    asm volatile("s_waitcnt lgkmcnt(0)");
    __builtin_amdgcn_sched_barrier(0);
  }

  {
    const float lt = lsh + __shfl_xor(lsh, 32);
    const float rl = __builtin_amdgcn_rcpf(lt);
    #pragma unroll
    for (int r = 0; r < 16; r++) {
      const int q = (r & 3) + 8 * (r >> 2) + 4 * hi;
      const float rr = lanepull(rl, q);
      unsigned short* op = Out + (size_t)(b * Sn + wqh + q) * Dn + h * HD;
      op[li]      = f2bf(o0h[r] * rr);
      op[32 + li] = f2bf(o1h[r] * rr);
    }
  }
  {
    const float lt = lsl + __shfl_xor(lsl, 32);
    const float rl = __builtin_amdgcn_rcpf(lt);
    #pragma unroll
    for (int r = 0; r < 16; r++) {
      const int q = (r & 3) + 8 * (r >> 2) + 4 * hi;
      const float rr = lanepull(rl, q);
      unsigned short* op = Out + (size_t)(b * Sn + wql + q) * Dn + h * HD;
      op[li]      = f2bf(o0l[r] * rr);
      op[32 + li] = f2bf(o1l[r] * rr);
    }
  }
}

// ---------------- tail: string_len -> float ----------------
__global__ void copy_len(const int* __restrict__ slen, float* __restrict__ dst, int n) {
  const int i = threadIdx.x;
  if (i < n) dst[i] = (float)slen[i];
}

extern "C" void kernel_launch(void* const* d_in, const int* in_sizes, int n_in,
                              void* d_out, int out_size, void* d_ws, size_t ws_size,
                              hipStream_t stream) {
  const float* X    = (const float*)d_in[0];
  const int*   slen = (const int*)d_in[1];
  const float* Wqkv = (const float*)d_in[2];
  const float* bqkv = (const float*)d_in[3];
  const float* Wo   = (const float*)d_in[4];
  const float* bo   = (const float*)d_in[5];
  float* out = (float*)d_out;

  char* ws = (char*)d_ws;
  unsigned char*  Xf8   = (unsigned char*)ws;                       // 8.4 MB (region 16 MB)
  unsigned char*  Wtq8  = (unsigned char*)(ws + 16777216);          // 3.1 MB (region 6 MB)
  unsigned short* Wto   = (unsigned short*)(ws + 16777216 + 6291456);
  unsigned short* QKVb  = (unsigned short*)(ws + 16777216 + 6291456 + 2097152);
  unsigned short* Attnb = (unsigned short*)ws;   // X dead after QKV GEMM; reuse

  cvt_f32_fp8<<<dim3(8192), dim3(256), 0, stream>>>(X, Xf8, Mrows * Dn);
  transpose_cvt_fp8<<<dim3(96, 32), dim3(32, 8), 0, stream>>>(Wqkv, Wtq8, Dn, D3);
  transpose_cvt<<<dim3(32, 32), dim3(32, 8), 0, stream>>>(Wo, Wto, Dn, Dn);

  gemm_fp8<<<dim3(64, 12), dim3(512), 0, stream>>>(Xf8, Wtq8, bqkv, QKVb, D3, Dn);
  attn_pair<<<dim3(64, 4), dim3(512), 0, stream>>>(QKVb, Attnb);
  gemm_bt2<false><<<dim3(64, 4), dim3(512), 0, stream>>>(Attnb, Wto, bo, d_out, Dn, Dn);
  copy_len<<<dim3(1), dim3(64), 0, stream>>>(slen, out + (size_t)Mrows * Dn, Bn);
}

// Round 20
// 152.044 us; speedup vs baseline: 1.2996x; 1.0416x over previous
//
#include <hip/hip_runtime.h>
#include <hip/hip_fp8.h>
#include <stdint.h>

typedef __attribute__((ext_vector_type(8))) short bf16x8;
typedef __attribute__((ext_vector_type(4))) float f32x4;
typedef __attribute__((ext_vector_type(16))) float f32x16;
typedef __attribute__((ext_vector_type(4))) unsigned short u16x4;

static constexpr int Bn = 4, Sn = 2048, Dn = 1024, Hn = 16, HD = 64;
static constexpr int Mrows = Bn * Sn;   // 8192
static constexpr int D3 = 3 * Dn;       // 3072

__device__ __forceinline__ unsigned short f2bf(float f) {
  unsigned int u = __float_as_uint(f);
  u += 0x7FFF + ((u >> 16) & 1);
  return (unsigned short)(u >> 16);
}

__device__ __forceinline__ unsigned char f2fp8(float f) {
  __hip_fp8_e4m3 v(f);
  return (unsigned char)v.__x;
}

__device__ __forceinline__ void gload16(const void* gptr, void* lptr) {
  __builtin_amdgcn_global_load_lds(
      (__attribute__((address_space(1))) void*)gptr,
      (__attribute__((address_space(3))) void*)lptr, 16, 0, 0);
}

__device__ __forceinline__ int swz8(int r) { return (r ^ (r >> 3)) & 7; }

__device__ __forceinline__ float vexp2(float x) {
#if __has_builtin(__builtin_amdgcn_exp2f)
  return __builtin_amdgcn_exp2f(x);
#else
  return exp2f(x);
#endif
}

__device__ __forceinline__ unsigned cvtpk(float lo, float hi) {
  unsigned r;
  asm("v_cvt_pk_bf16_f32 %0, %1, %2" : "=v"(r) : "v"(lo), "v"(hi));
  return r;
}

__device__ __forceinline__ float lanepull(float v, int srclane) {
  return __int_as_float(__builtin_amdgcn_ds_bpermute(srclane * 4, __float_as_int(v)));
}

// ---------------- elementwise f32 -> fp8 e4m3 ----------------
__global__ void cvt_f32_fp8(const float* __restrict__ in,
                            unsigned char* __restrict__ out, int n) {
  int i = (blockIdx.x * blockDim.x + threadIdx.x) * 4;
  if (i < n) {
    const float4 v = *(const float4*)(in + i);
    uchar4 o;
    o.x = f2fp8(v.x); o.y = f2fp8(v.y); o.z = f2fp8(v.z); o.w = f2fp8(v.w);
    *(uchar4*)(out + i) = o;
  }
}

// ---------------- W [K][N] f32 -> W^T [N][K] fp8 (scaled x64) ----------------
__global__ void transpose_cvt_fp8(const float* __restrict__ W,
                                  unsigned char* __restrict__ Wt, int K, int N) {
  __shared__ float tile[32][33];
  const int n0 = blockIdx.x * 32, k0 = blockIdx.y * 32;
  const int tx = threadIdx.x, ty = threadIdx.y;   // block (32,8)
  #pragma unroll
  for (int j = 0; j < 4; j++)
    tile[ty + 8 * j][tx] = W[(size_t)(k0 + ty + 8 * j) * N + n0 + tx];
  __syncthreads();
  #pragma unroll
  for (int j = 0; j < 4; j++)
    Wt[(size_t)(n0 + ty + 8 * j) * K + k0 + tx] = f2fp8(tile[tx][ty + 8 * j] * 64.0f);
}

// ---------------- 128x256 fp8 GEMM, BK=128: C = A[M,K] @ (64*Bt)[N,K]^T /64 + bias ----------------
// bt2 staging frame (128-B rows, swz8 16B-slot swizzle, 6 gloads, counted
// vmcnt(6), 2-barrier loop); rows hold 128 fp8 -> BK=128 (8 iters at K=1024).
// 64 MFMA/wave/iter via mfma_f32_16x16x32_fp8_fp8 (b64 frags).
// Epilogue un-scales W's x64 (acc * 1/64) then adds bias.
template<bool BF16_OUT>
__global__ __launch_bounds__(512, 1)
void gemm_fp8(const unsigned char* __restrict__ A,
              const unsigned char* __restrict__ Bt,
              const float* __restrict__ bias,
              void* __restrict__ Cout, int Nt, int Kt) {
  __shared__ __align__(128) unsigned char smem[98304];  // 2 x (A 16K + B 32K)
  const int tid = threadIdx.x;
  const int w = tid >> 6, lane = tid & 63;
  const int wm = w >> 2, wn = w & 3;
  const int lrow = lane & 15, lk = lane >> 4;
  const long brow = (long)blockIdx.x * 128;
  const long bcol = (long)blockIdx.y * 256;

  const int srow = tid >> 3;    // 0..63
  const int sslot = tid & 7;

  auto stage = [&](int k0, unsigned char* buf) {   // 6 gloads: 2 A + 4 B
    unsigned char* Ab = buf;
    unsigned char* Bb = buf + 16384;
    #pragma unroll
    for (int i = 0; i < 2; i++) {
      const int r = srow + 64 * i;
      gload16(A + (size_t)(brow + r) * Kt + k0 + ((sslot ^ swz8(r)) * 16),
              Ab + w * 1024 + i * 8192);
    }
    #pragma unroll
    for (int i = 0; i < 4; i++) {
      const int r = srow + 64 * i;
      gload16(Bt + (size_t)(bcol + r) * Kt + k0 + ((sslot ^ swz8(r)) * 16),
              Bb + w * 1024 + i * 8192);
    }
  };

  f32x4 acc[4][4] = {};

  stage(0, smem);

  const int ntile = Kt >> 7;          // BK = 128
  for (int t = 0; t < ntile; t++) {
    const int cur = t & 1;
    unsigned char* Ab = smem + cur * 49152;
    unsigned char* Bb = Ab + 16384;

    __builtin_amdgcn_s_barrier();     // retires t-1 readers of buf^1
    if (t + 1 < ntile) {
      stage((t + 1) << 7, smem + (cur ^ 1) * 49152);
      asm volatile("s_waitcnt vmcnt(6)");  // t's 6 loads done; t+1's in flight
    } else {
      asm volatile("s_waitcnt vmcnt(0)");
    }
    __builtin_amdgcn_sched_barrier(0);
    __builtin_amdgcn_s_barrier();     // buf t visible block-wide

    const int sub = (lk & 1) * 8;
    #pragma unroll
    for (int kk = 0; kk < 4; kk++) {
      const int s16 = kk * 2 + (lk >> 1);
      long av[4], bv[4];
      #pragma unroll
      for (int mt = 0; mt < 4; mt++) {
        const int r = wm * 64 + mt * 16 + lrow;
        av[mt] = *(const long*)(Ab + r * 128 + (((s16 ^ swz8(r)) << 4) + sub));
      }
      #pragma unroll
      for (int nt = 0; nt < 4; nt++) {
        const int r = wn * 64 + nt * 16 + lrow;
        bv[nt] = *(const long*)(Bb + r * 128 + (((s16 ^ swz8(r)) << 4) + sub));
      }
      __builtin_amdgcn_s_setprio(1);
      #pragma unroll
      for (int mt = 0; mt < 4; mt++)
        #pragma unroll
        for (int nt = 0; nt < 4; nt++)
          acc[mt][nt] = __builtin_amdgcn_mfma_f32_16x16x32_fp8_fp8(av[mt], bv[nt], acc[mt][nt], 0, 0, 0);
      __builtin_amdgcn_s_setprio(0);
    }
  }

  #pragma unroll
  for (int nt = 0; nt < 4; nt++) {
    const long col = bcol + wn * 64 + nt * 16 + lrow;
    const float bv2 = bias[col];
    #pragma unroll
    for (int mt = 0; mt < 4; mt++) {
      #pragma unroll
      for (int rr = 0; rr < 4; rr++) {
        const long row = brow + wm * 64 + mt * 16 + lk * 4 + rr;
        const float v = acc[mt][nt][rr] * 0.015625f + bv2;
        if (BF16_OUT)
          ((unsigned short*)Cout)[row * Nt + col] = f2bf(v);
        else
          ((float*)Cout)[row * Nt + col] = v;
      }
    }
  }
}

// ---------------- flash attention: sequential-pair balanced schedule ----------------
// (round-18 verified structure; epilogue now emits fp8 e4m3 for the proj GEMM)
__global__ __launch_bounds__(512, 1)
void attn_pair(const unsigned short* __restrict__ QKV,
               unsigned char* __restrict__ Out) {
  __shared__ __align__(128) unsigned char smem[65536]; // 2 x (16K K + 16K VT)
  const int tid  = threadIdx.x;
  const int w    = tid >> 6;
  const int lane = tid & 63;
  const int li = lane & 31, hi = lane >> 5;
  const int bh = blockIdx.x;
  const int b  = bh >> 4, h = bh & 15;
  const int p  = blockIdx.y;                 // pair index 0..3
  const int wqh = (7 - p) * 256 + w * 32;    // heavy subtile base
  const int wql = p * 256 + w * 32;          // light subtile base

  const float cexp = 0.18033688011112042f;   // (1/8) * log2(e)

  bf16x8 qfh[4], qfl[4];
  {
    const unsigned short* qp = QKV + (size_t)(b * Sn + wqh + li) * D3 + h * HD + hi * 8;
    #pragma unroll
    for (int ks = 0; ks < 4; ks++) qfh[ks] = *(const bf16x8*)(qp + ks * 16);
  }
  {
    const unsigned short* qp = QKV + (size_t)(b * Sn + wql + li) * D3 + h * HD + hi * 8;
    #pragma unroll
    for (int ks = 0; ks < 4; ks++) qfl[ks] = *(const bf16x8*)(qp + ks * 16);
  }

  f32x16 o0h = {}, o1h = {}, o0l = {}, o1l = {};
  float mh = -3.0e38f, lsh = 0.f, ml = -3.0e38f, lsl = 0.f;

  auto kstage = [&](int kb, unsigned char* Kb) {
    #pragma unroll
    for (int i = 0; i < 2; i++) {
      const int r    = w * 16 + i * 8 + (lane >> 3);
      const int slot = (lane & 7) ^ swz8(r);
      gload16(QKV + (size_t)(b * Sn + kb + r) * D3 + Dn + h * HD + slot * 8,
              Kb + w * 2048 + i * 1024);
    }
  };
  const int vkv8 = tid >> 3;          // 0..63
  const int vd0  = (tid & 7) * 8;
  auto vload = [&](int kb, int i) -> bf16x8 {
    return *(const bf16x8*)(QKV + (size_t)(b * Sn + kb + i * 64 + vkv8) * D3 + 2 * Dn + h * HD + vd0);
  };
  auto vwrite = [&](bf16x8 vv, int i, unsigned char* Vb) {
    const int kv = i * 64 + vkv8;
    #pragma unroll
    for (int jj = 0; jj < 8; jj++) {
      const int d  = vd0 + jj;
      const int vs = (d ^ (d >> 3)) & 15;
      *(unsigned short*)(Vb + d * 256 + (((kv >> 3) ^ vs) << 4) + (kv & 7) * 2) = (unsigned short)vv[jj];
    }
  };

  auto substep = [&](int s, int kb, const unsigned char* Kb, const unsigned char* Vb,
                     int wqX, bf16x8 (&qf)[4], f32x16& o0, f32x16& o1,
                     float& m, float& ls) {
    const int qrowX = wqX + li;
    f32x16 s0 = {}, s1 = {};
    const int r0 = s * 64 + li, r1 = s * 64 + 32 + li;
    __builtin_amdgcn_s_setprio(1);
    #pragma unroll
    for (int ks = 0; ks < 4; ks++) {
      const int slot = ks * 2 + hi;
      const bf16x8 k0 = *(const bf16x8*)(Kb + r0 * 128 + ((slot ^ swz8(r0)) * 16));
      const bf16x8 k1 = *(const bf16x8*)(Kb + r1 * 128 + ((slot ^ swz8(r1)) * 16));
      s0 = __builtin_amdgcn_mfma_f32_32x32x16_bf16(k0, qf[ks], s0, 0, 0, 0);
      s1 = __builtin_amdgcn_mfma_f32_32x32x16_bf16(k1, qf[ks], s1, 0, 0, 0);
    }
    __builtin_amdgcn_s_setprio(0);
    const int kbase = kb + s * 64;
    if (kbase + 63 > wqX) {
      #pragma unroll
      for (int r = 0; r < 16; r++) {
        const int kvl = (r & 3) + 8 * (r >> 2) + 4 * hi;
        if (kbase + kvl > qrowX)      s0[r] = -3.0e38f;
        if (kbase + 32 + kvl > qrowX) s1[r] = -3.0e38f;
      }
    }
    float t8[8];
    #pragma unroll
    for (int r = 0; r < 8; r++)
      t8[r] = fmaxf(fmaxf(s0[r], s0[r + 8]), fmaxf(s1[r], s1[r + 8]));
    float tmax = fmaxf(fmaxf(fmaxf(t8[0], t8[1]), fmaxf(t8[2], t8[3])),
                       fmaxf(fmaxf(t8[4], t8[5]), fmaxf(t8[6], t8[7])));
    tmax = fmaxf(tmax, __shfl_xor(tmax, 32));
    if (__any(tmax > m + 44.0f)) {
      const float mn   = fmaxf(m, tmax);
      const float corr = vexp2((m - mn) * cexp);
      m = mn;
      ls *= corr;
      #pragma unroll
      for (int r = 0; r < 16; r++) {
        const float cr = lanepull(corr, (r & 3) + 8 * (r >> 2) + 4 * hi);
        o0[r] *= cr; o1[r] *= cr;
      }
    }
    const float mc = m * cexp;
    f32x16 p0, p1;
    float psa = 0.f, psb = 0.f, psc = 0.f, psd = 0.f;
    #pragma unroll
    for (int r = 0; r < 16; r += 4) {
      p0[r] = vexp2(fmaf(s0[r], cexp, -mc));         psa += p0[r];
      p0[r + 1] = vexp2(fmaf(s0[r + 1], cexp, -mc)); psb += p0[r + 1];
      p0[r + 2] = vexp2(fmaf(s0[r + 2], cexp, -mc)); psc += p0[r + 2];
      p0[r + 3] = vexp2(fmaf(s0[r + 3], cexp, -mc)); psd += p0[r + 3];
    }
    #pragma unroll
    for (int r = 0; r < 16; r += 4) {
      p1[r] = vexp2(fmaf(s1[r], cexp, -mc));         psa += p1[r];
      p1[r + 1] = vexp2(fmaf(s1[r + 1], cexp, -mc)); psb += p1[r + 1];
      p1[r + 2] = vexp2(fmaf(s1[r + 2], cexp, -mc)); psc += p1[r + 2];
      p1[r + 3] = vexp2(fmaf(s1[r + 3], cexp, -mc)); psd += p1[r + 3];
    }
    ls += (psa + psb) + (psc + psd);

    auto mk_pa = [&](const f32x16& pp, int base) -> bf16x8 {
      const unsigned a0 = cvtpk(pp[base + 0], pp[base + 1]);
      const unsigned a1 = cvtpk(pp[base + 2], pp[base + 3]);
      const unsigned b0 = cvtpk(pp[base + 4], pp[base + 5]);
      const unsigned b1 = cvtpk(pp[base + 6], pp[base + 7]);
      const unsigned xa0 = __shfl_xor(a0, 32), xa1 = __shfl_xor(a1, 32);
      const unsigned xb0 = __shfl_xor(b0, 32), xb1 = __shfl_xor(b1, 32);
      union { unsigned u[4]; bf16x8 v; } pu;
      pu.u[0] = hi ? xb0 : a0;
      pu.u[1] = hi ? xb1 : a1;
      pu.u[2] = hi ? b0  : xa0;
      pu.u[3] = hi ? b1  : xa1;
      return pu.v;
    };
    bf16x8 pa[4];
    pa[0] = mk_pa(p0, 0); pa[1] = mk_pa(p0, 8);
    pa[2] = mk_pa(p1, 0); pa[3] = mk_pa(p1, 8);

    const int vs0 = (li ^ (li >> 3)) & 15;
    const int vs1 = ((32 + li) ^ ((32 + li) >> 3)) & 15;
    __builtin_amdgcn_s_setprio(1);
    #pragma unroll
    for (int k16 = 0; k16 < 4; k16++) {
      const int slot = s * 8 + k16 * 2 + hi;
      const bf16x8 vb0 = *(const bf16x8*)(Vb + li * 256 + ((slot ^ vs0) << 4));
      const bf16x8 vb1 = *(const bf16x8*)(Vb + (32 + li) * 256 + ((slot ^ vs1) << 4));
      o0 = __builtin_amdgcn_mfma_f32_32x32x16_bf16(pa[k16], vb0, o0, 0, 0, 0);
      o1 = __builtin_amdgcn_mfma_f32_32x32x16_bf16(pa[k16], vb1, o1, 0, 0, 0);
    }
    __builtin_amdgcn_s_setprio(0);
  };

  kstage(0, smem);
  {
    bf16x8 va = vload(0, 0), vb = vload(0, 1);
    vwrite(va, 0, smem + 16384);
    vwrite(vb, 1, smem + 16384);
  }
  asm volatile("s_waitcnt lgkmcnt(0)");
  __builtin_amdgcn_sched_barrier(0);

  const int nt = 16 - 2 * p;   // tiles needed by the heavy q-tile
  for (int t = 0; t < nt; t++) {
    const int kb  = t << 7;
    const int cur = t & 1;
    unsigned char* Kb = smem + cur * 32768;
    unsigned char* Vb = Kb + 16384;
    const bool pre = (t + 1 < nt);
    bf16x8 vna, vnb;

    __builtin_amdgcn_s_barrier();
    if (pre) {
      kstage(kb + 128, smem + (cur ^ 1) * 32768);
      vna = vload(kb + 128, 0);
      vnb = vload(kb + 128, 1);
    }

    if (kb <= wqh + 31) {
      substep(0, kb, Kb, Vb, wqh, qfh, o0h, o1h, mh, lsh);
      if (kb + 64 <= wqh + 31) substep(1, kb, Kb, Vb, wqh, qfh, o0h, o1h, mh, lsh);
    }
    if (kb <= wql + 31) {
      substep(0, kb, Kb, Vb, wql, qfl, o0l, o1l, ml, lsl);
      if (kb + 64 <= wql + 31) substep(1, kb, Kb, Vb, wql, qfl, o0l, o1l, ml, lsl);
    }

    if (pre) {
      unsigned char* Vn = smem + (cur ^ 1) * 32768 + 16384;
      vwrite(vna, 0, Vn);
      vwrite(vnb, 1, Vn);
    }
    asm volatile("s_waitcnt lgkmcnt(0)");
    __builtin_amdgcn_sched_barrier(0);
  }

  // ---- epilogue: O / l -> fp8 e4m3 (feeds the fp8 proj GEMM) ----
  {
    const float lt = lsh + __shfl_xor(lsh, 32);
    const float rl = __builtin_amdgcn_rcpf(lt);
    #pragma unroll
    for (int r = 0; r < 16; r++) {
      const int q = (r & 3) + 8 * (r >> 2) + 4 * hi;
      const float rr = lanepull(rl, q);
      unsigned char* op = Out + (size_t)(b * Sn + wqh + q) * Dn + h * HD;
      op[li]      = f2fp8(o0h[r] * rr);
      op[32 + li] = f2fp8(o1h[r] * rr);
    }
  }
  {
    const float lt = lsl + __shfl_xor(lsl, 32);
    const float rl = __builtin_amdgcn_rcpf(lt);
    #pragma unroll
    for (int r = 0; r < 16; r++) {
      const int q = (r & 3) + 8 * (r >> 2) + 4 * hi;
      const float rr = lanepull(rl, q);
      unsigned char* op = Out + (size_t)(b * Sn + wql + q) * Dn + h * HD;
      op[li]      = f2fp8(o0l[r] * rr);
      op[32 + li] = f2fp8(o1l[r] * rr);
    }
  }
}

// ---------------- tail: string_len -> float ----------------
__global__ void copy_len(const int* __restrict__ slen, float* __restrict__ dst, int n) {
  const int i = threadIdx.x;
  if (i < n) dst[i] = (float)slen[i];
}

extern "C" void kernel_launch(void* const* d_in, const int* in_sizes, int n_in,
                              void* d_out, int out_size, void* d_ws, size_t ws_size,
                              hipStream_t stream) {
  const float* X    = (const float*)d_in[0];
  const int*   slen = (const int*)d_in[1];
  const float* Wqkv = (const float*)d_in[2];
  const float* bqkv = (const float*)d_in[3];
  const float* Wo   = (const float*)d_in[4];
  const float* bo   = (const float*)d_in[5];
  float* out = (float*)d_out;

  char* ws = (char*)d_ws;
  unsigned char*  Xf8   = (unsigned char*)ws;                       // 8.4 MB (region 16 MB)
  unsigned char*  Wtq8  = (unsigned char*)(ws + 16777216);          // 3.1 MB (region 6 MB)
  unsigned char*  Wto8  = (unsigned char*)(ws + 16777216 + 6291456); // 1.05 MB (region 2 MB)
  unsigned short* QKVb  = (unsigned short*)(ws + 16777216 + 6291456 + 2097152);
  unsigned char*  Attnb = (unsigned char*)ws;   // X dead after QKV GEMM; reuse (fp8)

  cvt_f32_fp8<<<dim3(8192), dim3(256), 0, stream>>>(X, Xf8, Mrows * Dn);
  transpose_cvt_fp8<<<dim3(96, 32), dim3(32, 8), 0, stream>>>(Wqkv, Wtq8, Dn, D3);
  transpose_cvt_fp8<<<dim3(32, 32), dim3(32, 8), 0, stream>>>(Wo, Wto8, Dn, Dn);

  gemm_fp8<true><<<dim3(64, 12), dim3(512), 0, stream>>>(Xf8, Wtq8, bqkv, (void*)QKVb, D3, Dn);
  attn_pair<<<dim3(64, 4), dim3(512), 0, stream>>>(QKVb, Attnb);
  gemm_fp8<false><<<dim3(64, 4), dim3(512), 0, stream>>>(Attnb, Wto8, bo, d_out, Dn, Dn);
  copy_len<<<dim3(1), dim3(64), 0, stream>>>(slen, out + (size_t)Mrows * Dn, Bn);
}